// Round 1
// baseline (114.981 us; speedup 1.0000x reference)
//
#include <hip/hip_runtime.h>
#include <hip/hip_bf16.h>
#include <math.h>

#define NCLS 151
#define NQ   100
#define NB   2
#define HW   16384   // 128*128
#define NCO  150     // classes after dropping class 0
#define OUTW 512

// ---------------- Kernel 1: row softmax over 151 classes ----------------
// grid = B*Q blocks, 64 threads (one wave per row)
__global__ __launch_bounds__(64) void softmax_k(const float* __restrict__ logits,
                                                float* __restrict__ scores) {
    int row = blockIdx.x;                  // b*NQ + q
    const float* in = logits + row * NCLS;
    float* op = scores + row * NCLS;
    int lane = threadIdx.x;

    float v0 = in[lane];
    float v1 = in[lane + 64];
    float v2 = (lane < NCLS - 128) ? in[lane + 128] : -1e30f;

    float m = fmaxf(fmaxf(v0, v1), v2);
    #pragma unroll
    for (int o = 32; o; o >>= 1) m = fmaxf(m, __shfl_xor(m, o));

    float e0 = __expf(v0 - m);
    float e1 = __expf(v1 - m);
    float e2 = (lane < NCLS - 128) ? __expf(v2 - m) : 0.f;

    float s = e0 + e1 + e2;
    #pragma unroll
    for (int o = 32; o; o >>= 1) s += __shfl_xor(s, o);

    float inv = 1.f / s;
    op[lane] = e0 * inv;
    op[lane + 64] = e1 * inv;
    if (lane < NCLS - 128) op[lane + 128] = e2 * inv;
}

// ---------------- Kernel 2: sigmoid + einsum -> seg[b][co][p] ----------------
// block: 256 threads, covers 64 pixels x 150 channels for one batch b.
// grid = (HW/64, B)
// Per thread: 4 pixels x 10 channels register tile; sigmoid + shifted scores in LDS.
__global__ __launch_bounds__(256) void einsum_k(const float* __restrict__ masks,
                                                const float* __restrict__ scores,
                                                float* __restrict__ seg) {
    __shared__ float s_sig[NQ][64];    // 25.6 KB  sigmoid(mask) tile
    __shared__ float s_sc[NQ][152];    // 60.8 KB  scores[b][q][1..150] (shifted)

    int b   = blockIdx.y;
    int pb  = blockIdx.x * 64;
    int tid = threadIdx.x;

    // stage sigmoid tile (coalesced)
    for (int i = tid; i < NQ * 64; i += 256) {
        int q = i >> 6, p = i & 63;
        float x = masks[(size_t)(b * NQ + q) * HW + pb + p];
        s_sig[q][p] = 1.f / (1.f + __expf(-x));
    }
    // stage shifted scores
    for (int i = tid; i < NQ * NCO; i += 256) {
        int q = i / NCO, c = i - q * NCO;
        s_sc[q][c] = scores[(b * NQ + q) * NCLS + c + 1];
    }
    __syncthreads();

    int pg = tid & 15;       // 16 pixel groups of 4
    int cg = tid >> 4;       // 16 channel groups of 10 (group 15 idle: 150 channels)
    if (cg >= 15) return;    // no further barriers below

    int p0 = pg * 4;
    int c0 = cg * 10;

    float acc[10][4];
    #pragma unroll
    for (int j = 0; j < 10; ++j)
        #pragma unroll
        for (int i = 0; i < 4; ++i) acc[j][i] = 0.f;

    for (int q = 0; q < NQ; ++q) {
        float4 sv = *(const float4*)&s_sig[q][p0];
        float sc[10];
        const float2* scp = (const float2*)&s_sc[q][c0];   // c0 even -> 8B aligned
        #pragma unroll
        for (int j = 0; j < 5; ++j) {
            float2 t = scp[j];
            sc[2 * j] = t.x;
            sc[2 * j + 1] = t.y;
        }
        #pragma unroll
        for (int j = 0; j < 10; ++j) {
            acc[j][0] += sc[j] * sv.x;
            acc[j][1] += sc[j] * sv.y;
            acc[j][2] += sc[j] * sv.z;
            acc[j][3] += sc[j] * sv.w;
        }
    }

    #pragma unroll
    for (int j = 0; j < 10; ++j) {
        float4 o;
        o.x = acc[j][0]; o.y = acc[j][1]; o.z = acc[j][2]; o.w = acc[j][3];
        *(float4*)&seg[(size_t)(b * NCO + c0 + j) * HW + pb + p0] = o;
    }
}

// ---------------- Kernel 3: bilinear 128->512 upsample ----------------
// one float4 (4 consecutive w outputs) per thread; exact jax half-pixel mapping.
// t = (i+0.5)/4 - 0.5 ; i = 4k+r -> i0 = k - (r<2), f = {0.625,0.875,0.125,0.375}
__global__ __launch_bounds__(256) void resize_k(const float* __restrict__ seg,
                                                float* __restrict__ out) {
    int idx = blockIdx.x * 256 + threadIdx.x;   // index of one float4 of output
    int w4 = idx & 127;            // 128 float4 per output row
    int h  = (idx >> 7) & 511;
    int bc = idx >> 16;            // [0, 300): b*150 + co

    int hr = h & 3;
    int ih0 = (h >> 2) - (hr < 2 ? 1 : 0);
    float fh = 0.125f + 0.25f * (float)((hr + 2) & 3);
    int ih1 = min(ih0 + 1, 127);
    ih0 = max(ih0, 0);

    int k = w4;
    int iwm1 = max(k - 1, 0);
    int iwp1 = min(k + 1, 127);

    const float* r0 = seg + (size_t)bc * HW + ih0 * 128;
    const float* r1 = seg + (size_t)bc * HW + ih1 * 128;

    float a0 = r0[iwm1], a1 = r0[k], a2 = r0[iwp1];
    float b0 = r1[iwm1], b1 = r1[k], b2 = r1[iwp1];

    // w-lerps (top row, bottom row) for the 4 outputs
    float t0 = a0 + 0.625f * (a1 - a0);
    float t1 = a0 + 0.875f * (a1 - a0);
    float t2 = a1 + 0.125f * (a2 - a1);
    float t3 = a1 + 0.375f * (a2 - a1);
    float u0 = b0 + 0.625f * (b1 - b0);
    float u1 = b0 + 0.875f * (b1 - b0);
    float u2 = b1 + 0.125f * (b2 - b1);
    float u3 = b1 + 0.375f * (b2 - b1);

    float4 o;
    o.x = t0 + fh * (u0 - t0);
    o.y = t1 + fh * (u1 - t1);
    o.z = t2 + fh * (u2 - t2);
    o.w = t3 + fh * (u3 - t3);

    *(float4*)(out + (size_t)idx * 4) = o;
}

extern "C" void kernel_launch(void* const* d_in, const int* in_sizes, int n_in,
                              void* d_out, int out_size, void* d_ws, size_t ws_size,
                              hipStream_t stream) {
    const float* logits = (const float*)d_in[0];
    const float* masks  = (const float*)d_in[1];
    float* out = (float*)d_out;

    float* scores = (float*)d_ws;                        // 200*151*4 = 120,800 B
    float* seg    = (float*)((char*)d_ws + (1 << 17));   // 19,660,800 B

    softmax_k<<<dim3(NB * NQ), dim3(64), 0, stream>>>(logits, scores);
    einsum_k<<<dim3(HW / 64, NB), dim3(256), 0, stream>>>(masks, scores, seg);

    int total4 = NB * NCO * OUTW * (OUTW / 4);           // 19,660,800 float4s
    resize_k<<<dim3(total4 / 256), dim3(256), 0, stream>>>(seg, out);
}

// Round 2
// 87.536 us; speedup vs baseline: 1.3135x; 1.3135x over previous
//
#include <hip/hip_runtime.h>
#include <hip/hip_bf16.h>
#include <math.h>

#define NCLS 151
#define NQ   100
#define NB   2
#define HW   16384   // 128*128
#define NCO  150     // classes after dropping class 0
#define OUTW 512
#define KPAD 128     // Q padded to 128 (4 k-steps of 32)
#define CPAD 160     // C padded to 160 (10 tiles of 16)
#define LROW 136     // LDS row length in bf16 (272 B stride -> conflict-free b128 reads)

using short8 = __attribute__((ext_vector_type(8))) short;
using f32x4  = __attribute__((ext_vector_type(4))) float;

static __device__ __forceinline__ ushort f2bf(float x) {
    union { float f; unsigned u; } v; v.f = x;
    unsigned r = v.u + 0x7fff + ((v.u >> 16) & 1);   // round-to-nearest-even
    return (ushort)(r >> 16);
}

// ---------------- Kernel 1: softmax -> transposed bf16 scores A[b][c][q] ----------------
// grid = NB * 128 (q-padded); blocks with q>=100 write zero pad columns.
// c = class-1 (class 0 dropped); rows 150..159 zero pad.
__global__ __launch_bounds__(64) void softmax_k(const float* __restrict__ logits,
                                                ushort* __restrict__ scoresT) {
    int q = blockIdx.x & 127;
    int b = blockIdx.x >> 7;
    int lane = threadIdx.x;
    ushort* A = scoresT + (size_t)b * CPAD * KPAD;

    if (q >= NQ) {   // zero pad columns q in [100,128) for all 160 rows
        A[lane * KPAD + q] = 0;
        A[(lane + 64) * KPAD + q] = 0;
        if (lane < 32) A[(lane + 128) * KPAD + q] = 0;
        return;
    }

    const float* in = logits + (size_t)(b * NQ + q) * NCLS;
    float v0 = in[lane];
    float v1 = in[lane + 64];
    float v2 = (lane < NCLS - 128) ? in[lane + 128] : -1e30f;

    float m = fmaxf(fmaxf(v0, v1), v2);
    #pragma unroll
    for (int o = 32; o; o >>= 1) m = fmaxf(m, __shfl_xor(m, o));

    float e0 = __expf(v0 - m);
    float e1 = __expf(v1 - m);
    float e2 = (lane < NCLS - 128) ? __expf(v2 - m) : 0.f;

    float s = e0 + e1 + e2;
    #pragma unroll
    for (int o = 32; o; o >>= 1) s += __shfl_xor(s, o);

    float inv = 1.f / s;
    // classes: lane (c=lane-1), lane+64 (c=lane+63), lane+128 (c=lane+127, lane<23)
    if (lane >= 1) A[(lane - 1) * KPAD + q] = f2bf(e0 * inv);
    A[(lane + 63) * KPAD + q] = f2bf(e1 * inv);
    if (lane < 23)       A[(lane + 127) * KPAD + q] = f2bf(e2 * inv);
    else if (lane < 33)  A[(lane + 127) * KPAD + q] = 0;   // c-pad rows 150..159
}

// ---------------- Kernel 2: MFMA einsum seg[b][c][p] = sum_q A[c][q]*sigmoid(M[q][p]) ----
// block = 256 threads (4 waves), tile = 160 c x 64 p, K = 128 (padded Q).
// grid = (HW/64, NB)
__global__ __launch_bounds__(256) void einsum_mfma_k(const float* __restrict__ masks,
                                                     const ushort* __restrict__ scoresT,
                                                     float* __restrict__ seg) {
    __shared__ __align__(16) ushort s_a[CPAD][LROW];   // 43520 B
    __shared__ __align__(16) ushort s_bt[64][LROW];    // 17408 B

    int b   = blockIdx.y;
    int pb  = blockIdx.x * 64;
    int tid = threadIdx.x;

    // stage A tile (whole 160x128, 16B chunks, coalesced)
    {
        const float4* src = (const float4*)(scoresT + (size_t)b * CPAD * KPAD);
        #pragma unroll
        for (int t = 0; t < 10; ++t) {
            int i = tid + t * 256;           // 2560 chunks total
            int c = i >> 4, kc = i & 15;
            float4 v = src[i];
            *(float4*)&s_a[c][kc * 8] = v;
        }
    }
    // stage B^T (sigmoid, transposed): s_bt[p][q]
    for (int i = tid; i < 64 * NQ; i += 256) {
        int q = i >> 6, p = i & 63;
        float x = masks[(size_t)(b * NQ + q) * HW + pb + p];
        s_bt[p][q] = f2bf(1.f / (1.f + __expf(-x)));
    }
    for (int i = tid; i < 64 * (KPAD - NQ); i += 256) {   // zero q-pad
        int q = NQ + (i >> 6), p = i & 63;
        s_bt[p][q] = 0;
    }
    __syncthreads();

    int wid = tid >> 6, lane = tid & 63;
    int pr = lane & 15;          // fragment row/col index
    int kg = lane >> 4;          // k-group 0..3
    int pw = wid * 16;           // wave's pixel sub-tile

    f32x4 acc[10];
    #pragma unroll
    for (int ct = 0; ct < 10; ++ct) acc[ct] = (f32x4){0.f, 0.f, 0.f, 0.f};

    #pragma unroll
    for (int ks = 0; ks < 4; ++ks) {
        short8 bf = *(const short8*)&s_bt[pw + pr][ks * 32 + kg * 8];
        #pragma unroll
        for (int ct = 0; ct < 10; ++ct) {
            short8 af = *(const short8*)&s_a[ct * 16 + pr][ks * 32 + kg * 8];
            acc[ct] = __builtin_amdgcn_mfma_f32_16x16x32_bf16(af, bf, acc[ct], 0, 0, 0);
        }
    }

    // D layout: row(c-local) = kg*4+j, col(p-local) = pr  [verified m89/m91]
    size_t segb = (size_t)b * NCO * HW + pb + pw + pr;
    #pragma unroll
    for (int ct = 0; ct < 10; ++ct) {
        int c0 = ct * 16 + kg * 4;
        #pragma unroll
        for (int j = 0; j < 4; ++j) {
            int c = c0 + j;
            if (c < NCO) seg[segb + (size_t)c * HW] = acc[ct][j];
        }
    }
}

// ---------------- Kernel 3: bilinear 128->512 upsample ----------------
__global__ __launch_bounds__(256) void resize_k(const float* __restrict__ seg,
                                                float* __restrict__ out) {
    int idx = blockIdx.x * 256 + threadIdx.x;   // one float4 of output
    int w4 = idx & 127;
    int h  = (idx >> 7) & 511;
    int bc = idx >> 16;            // [0, 300)

    int hr = h & 3;
    int ih0 = (h >> 2) - (hr < 2 ? 1 : 0);
    float fh = 0.125f + 0.25f * (float)((hr + 2) & 3);
    int ih1 = min(ih0 + 1, 127);
    ih0 = max(ih0, 0);

    int k = w4;
    int iwm1 = max(k - 1, 0);
    int iwp1 = min(k + 1, 127);

    const float* r0 = seg + (size_t)bc * HW + ih0 * 128;
    const float* r1 = seg + (size_t)bc * HW + ih1 * 128;

    float a0 = r0[iwm1], a1 = r0[k], a2 = r0[iwp1];
    float b0 = r1[iwm1], b1 = r1[k], b2 = r1[iwp1];

    float t0 = a0 + 0.625f * (a1 - a0);
    float t1 = a0 + 0.875f * (a1 - a0);
    float t2 = a1 + 0.125f * (a2 - a1);
    float t3 = a1 + 0.375f * (a2 - a1);
    float u0 = b0 + 0.625f * (b1 - b0);
    float u1 = b0 + 0.875f * (b1 - b0);
    float u2 = b1 + 0.125f * (b2 - b1);
    float u3 = b1 + 0.375f * (b2 - b1);

    float4 o;
    o.x = t0 + fh * (u0 - t0);
    o.y = t1 + fh * (u1 - t1);
    o.z = t2 + fh * (u2 - t2);
    o.w = t3 + fh * (u3 - t3);

    *(float4*)(out + (size_t)idx * 4) = o;
}

extern "C" void kernel_launch(void* const* d_in, const int* in_sizes, int n_in,
                              void* d_out, int out_size, void* d_ws, size_t ws_size,
                              hipStream_t stream) {
    const float* logits = (const float*)d_in[0];
    const float* masks  = (const float*)d_in[1];
    float* out = (float*)d_out;

    ushort* scoresT = (ushort*)d_ws;                      // 2*160*128*2 = 81,920 B
    float*  seg     = (float*)((char*)d_ws + (1 << 17));  // 2*150*16384*4 = 19,660,800 B

    softmax_k<<<dim3(NB * 128), dim3(64), 0, stream>>>(logits, scoresT);
    einsum_mfma_k<<<dim3(HW / 64, NB), dim3(256), 0, stream>>>(masks, scoresT, seg);

    int total4 = NB * NCO * OUTW * (OUTW / 4);            // 19,660,800 float4s
    resize_k<<<dim3(total4 / 256), dim3(256), 0, stream>>>(seg, out);
}

// Round 3
// 77.925 us; speedup vs baseline: 1.4755x; 1.1233x over previous
//
#include <hip/hip_runtime.h>
#include <hip/hip_bf16.h>
#include <math.h>

#define NCLS 151
#define NQ   100
#define NB   2
#define HW   16384   // 128*128
#define NCO  150     // classes after dropping class 0
#define OUTW 512
#define KPAD 128     // Q padded to 128
#define CPAD 160     // C padded to 160
#define CBLK 32      // classes per block (5 c-splits)
#define AROW 136     // s_a row stride in ushort (272 B)
#define BROW 72      // s_bt row stride in ushort (144 B)
#define SROW 130     // s_seg row stride in float

using short8  = __attribute__((ext_vector_type(8))) short;
using short4v = __attribute__((ext_vector_type(4))) short;
using f32x4   = __attribute__((ext_vector_type(4))) float;

static __device__ __forceinline__ ushort f2bf(float x) {
    union { float f; unsigned u; } v; v.f = x;
    unsigned r = v.u + 0x7fff + ((v.u >> 16) & 1);   // RNE
    return (ushort)(r >> 16);
}

// ---------------- Kernel 1: softmax -> transposed bf16 scores A[b][c][q] ----------------
__global__ __launch_bounds__(64) void softmax_k(const float* __restrict__ logits,
                                                ushort* __restrict__ scoresT) {
    int q = blockIdx.x & 127;
    int b = blockIdx.x >> 7;
    int lane = threadIdx.x;
    ushort* A = scoresT + (size_t)b * CPAD * KPAD;

    if (q >= NQ) {   // zero pad columns q in [100,128)
        A[lane * KPAD + q] = 0;
        A[(lane + 64) * KPAD + q] = 0;
        if (lane < 32) A[(lane + 128) * KPAD + q] = 0;
        return;
    }

    const float* in = logits + (size_t)(b * NQ + q) * NCLS;
    float v0 = in[lane];
    float v1 = in[lane + 64];
    float v2 = (lane < NCLS - 128) ? in[lane + 128] : -1e30f;

    float m = fmaxf(fmaxf(v0, v1), v2);
    #pragma unroll
    for (int o = 32; o; o >>= 1) m = fmaxf(m, __shfl_xor(m, o));

    float e0 = __expf(v0 - m);
    float e1 = __expf(v1 - m);
    float e2 = (lane < NCLS - 128) ? __expf(v2 - m) : 0.f;

    float s = e0 + e1 + e2;
    #pragma unroll
    for (int o = 32; o; o >>= 1) s += __shfl_xor(s, o);

    float inv = 1.f / s;
    if (lane >= 1) A[(lane - 1) * KPAD + q] = f2bf(e0 * inv);
    A[(lane + 63) * KPAD + q] = f2bf(e1 * inv);
    if (lane < 23)       A[(lane + 127) * KPAD + q] = f2bf(e2 * inv);
    else if (lane < 33)  A[(lane + 127) * KPAD + q] = 0;   // c-pad rows
}

// ---------------- Kernel 2: fused MFMA einsum + bilinear resize ----------------
// block: 512 thr (8 waves). grid: (128 row-pairs, NB*5 c-splits).
// Computes seg rows r, r+1 (32 classes x 256 px) in LDS, emits out rows 4r+2..4r+5
// (r=0 also rows 0..1; r=127 only 510..511).
__global__ __launch_bounds__(512) void fused_k(const float* __restrict__ masks,
                                               const ushort* __restrict__ scoresT,
                                               float* __restrict__ out) {
    __shared__ __align__(16) ushort s_a[CBLK][AROW];    //  8,704 B
    __shared__ __align__(16) ushort s_bt[256][BROW];    // 36,864 B
    __shared__ float s_seg[2][CBLK][SROW];              // 33,280 B

    int r   = blockIdx.x;            // seg row pair base
    int b   = blockIdx.y / 5;
    int cs  = blockIdx.y % 5;
    int tid = threadIdx.x;
    int r1  = min(r + 1, 127);

    // ---- stage A slice (32 c x 128 k bf16), one float4 chunk per thread ----
    {
        const float4* src = (const float4*)scoresT;
        int base = (b * CPAD + cs * CBLK) * (KPAD / 8);
        float4 v = src[base + tid];              // 512 chunks exactly
        int c = tid >> 4, kc = tid & 15;
        *(float4*)&s_a[c][kc * 8] = v;
    }

    int wid = tid >> 6, lane = tid & 63;
    int pr = lane & 15, kg = lane >> 4;

    f32x4 acc[2][2];
    #pragma unroll
    for (int ct = 0; ct < 2; ++ct)
        #pragma unroll
        for (int nt = 0; nt < 2; ++nt) acc[ct][nt] = (f32x4){0.f, 0.f, 0.f, 0.f};

    #pragma unroll
    for (int kc2 = 0; kc2 < 2; ++kc2) {
        // ---- stage B^T chunk: s_bt[p][kk], kk = k - kc2*64 in [0,64) ----
        #pragma unroll
        for (int i0 = 0; i0 < 4096; i0 += 512) {
            int i = i0 + tid;
            int p = i & 255, kk4 = i >> 8;               // kk4 uniform per wave
            int gpix = ((p < 128) ? r : r1) * 128 + (p & 127);
            short4v sv;
            #pragma unroll
            for (int e = 0; e < 4; ++e) {
                int gk = kc2 * 64 + kk4 * 4 + e;
                float x = (gk < NQ) ? masks[(size_t)(b * NQ + gk) * HW + gpix] : 0.f;
                float s = (gk < NQ) ? 1.f / (1.f + __expf(-x)) : 0.f;
                sv[e] = (short)f2bf(s);
            }
            *(short4v*)&s_bt[p][kk4 * 4] = sv;
        }
        __syncthreads();

        // ---- MFMA: 2 k-steps x 2 c-tiles x 2 n-tiles ----
        #pragma unroll
        for (int ks = 0; ks < 2; ++ks) {
            short8 bf0 = *(const short8*)&s_bt[wid * 32 + pr][ks * 32 + kg * 8];
            short8 bf1 = *(const short8*)&s_bt[wid * 32 + 16 + pr][ks * 32 + kg * 8];
            #pragma unroll
            for (int ct = 0; ct < 2; ++ct) {
                short8 af = *(const short8*)&s_a[ct * 16 + pr][kc2 * 64 + ks * 32 + kg * 8];
                acc[ct][0] = __builtin_amdgcn_mfma_f32_16x16x32_bf16(af, bf0, acc[ct][0], 0, 0, 0);
                acc[ct][1] = __builtin_amdgcn_mfma_f32_16x16x32_bf16(af, bf1, acc[ct][1], 0, 0, 0);
            }
        }
        __syncthreads();
    }

    // ---- acc -> s_seg (D layout: row = kg*4+j, col = pr) ----
    #pragma unroll
    for (int ct = 0; ct < 2; ++ct)
        #pragma unroll
        for (int nt = 0; nt < 2; ++nt) {
            int p = wid * 32 + nt * 16 + pr;
            int rs = p >> 7, px = p & 127;
            #pragma unroll
            for (int j = 0; j < 4; ++j) {
                int c = ct * 16 + kg * 4 + j;
                s_seg[rs][c][px] = acc[ct][nt][j];
            }
        }
    __syncthreads();

    // ---- emission: bilinear resize from LDS, coalesced float4 stores ----
    int NR = (r == 0) ? 6 : ((r == 127) ? 2 : 4);
    int cbase = cs * CBLK;
    for (int ri = 0; ri < NR; ++ri) {
        int h = (r == 0) ? ri : (4 * r + 2 + ri);
        float fh = (r == 0) ? ((ri < 2) ? 0.f : 0.125f + 0.25f * (float)(ri - 2))
                            : (0.125f + 0.25f * (float)ri);
        for (int it = tid; it < CBLK * 128; it += 512) {
            int k = it & 127;
            int c = it >> 7;
            int cg = cbase + c;
            if (cg >= NCO) break;                 // wave-uniform (c const per wave)
            int km = max(k - 1, 0), kp = min(k + 1, 127);
            const float* s0 = s_seg[0][c];
            const float* s1 = s_seg[1][c];
            float a0 = s0[km], a1 = s0[k], a2 = s0[kp];
            float b0 = s1[km], b1 = s1[k], b2 = s1[kp];

            float t0 = a0 + 0.625f * (a1 - a0);
            float t1 = a0 + 0.875f * (a1 - a0);
            float t2 = a1 + 0.125f * (a2 - a1);
            float t3 = a1 + 0.375f * (a2 - a1);
            float u0 = b0 + 0.625f * (b1 - b0);
            float u1 = b0 + 0.875f * (b1 - b0);
            float u2 = b1 + 0.125f * (b2 - b1);
            float u3 = b1 + 0.375f * (b2 - b1);

            float4 o;
            o.x = t0 + fh * (u0 - t0);
            o.y = t1 + fh * (u1 - t1);
            o.z = t2 + fh * (u2 - t2);
            o.w = t3 + fh * (u3 - t3);

            *(float4*)(out + ((size_t)(b * NCO + cg) * OUTW + h) * OUTW + 4 * k) = o;
        }
    }
}

extern "C" void kernel_launch(void* const* d_in, const int* in_sizes, int n_in,
                              void* d_out, int out_size, void* d_ws, size_t ws_size,
                              hipStream_t stream) {
    const float* logits = (const float*)d_in[0];
    const float* masks  = (const float*)d_in[1];
    float* out = (float*)d_out;

    ushort* scoresT = (ushort*)d_ws;   // 2*160*128*2 = 81,920 B

    softmax_k<<<dim3(NB * 128), dim3(64), 0, stream>>>(logits, scoresT);
    fused_k<<<dim3(128, NB * 5), dim3(512), 0, stream>>>(masks, scoresT, out);
}